// Round 15
// baseline (70.964 us; speedup 1.0000x reference)
//
#include <hip/hip_runtime.h>
#include <hip/hip_fp16.h>

#define LN 63
#define BATCHN 16384

typedef _Float16 f16x8 __attribute__((ext_vector_type(8)));  // 8 f16 in 4 VGPRs
typedef _Float16 h2    __attribute__((ext_vector_type(2)));  // packed pair
typedef __attribute__((ext_vector_type(4))) float f32x4;

__device__ __forceinline__ float fast_exp(float v) {
    return __builtin_amdgcn_exp2f(v * 1.4426950408889634f);
}
__device__ __forceinline__ unsigned short f2h(float f) {
    _Float16 h = (_Float16)f;                  // v_cvt_f16_f32 (RNE)
    return __builtin_bit_cast(unsigned short, h);
}
__device__ __forceinline__ unsigned int pk2h(float a, float b) {
    return (unsigned int)f2h(a) | ((unsigned int)f2h(b) << 16);
}

// Packed Padé(5,4) tanh: 2 values per instruction, exact integer coeffs.
// tanh v ~= v(945+105v^2+v^4)/(945+420v^2+15v^4); input clamp +-4.5 keeps f16
// in range (num<=15.7k<65504) and caps err at 1-tanh(4.5)=1.8e-4; output clamp
// to +-1 handles the >=1 overshoot of the rational beyond |v|~3.9.
__device__ __forceinline__ h2 tanh_pk(float a, float b) {
    const h2 c945 = {(_Float16)945.0f, (_Float16)945.0f};
    const h2 c105 = {(_Float16)105.0f, (_Float16)105.0f};
    const h2 c420 = {(_Float16)420.0f, (_Float16)420.0f};
    const h2 c15  = {(_Float16)15.0f,  (_Float16)15.0f};
    const h2 clim = {(_Float16)4.5f,   (_Float16)4.5f};
    const h2 cone = {(_Float16)1.0f,   (_Float16)1.0f};
    // R13 fix: builtin returns __fp16 ext_vector(2); bit_cast to h2 (same bits)
    h2 v = __builtin_bit_cast(h2, __builtin_amdgcn_cvt_pkrtz(a, b));
    v = __builtin_elementwise_min(v, clim);            // v_pk_min_f16
    v = __builtin_elementwise_max(v, -clim);
    h2 v2  = v * v;                                    // v_pk_mul_f16
    h2 num = v * (v2 * (v2 + c105) + c945);            // pk_add + pk_fma + pk_mul
    h2 den = v2 * (v2 * c15 + c420) + c945;            // 2x pk_fma
    __half2 r = h2rcp(__builtin_bit_cast(__half2, den));   // 2x v_rcp_f16
    h2 res = num * __builtin_bit_cast(h2, r);
    res = __builtin_elementwise_min(res, cone);
    res = __builtin_elementwise_max(res, -cone);
    return res;
}

// kappa j-index for W2/W3 fragment element e (derived from R6's verified LDS
// reads): e<4 -> 32s+4g+e ; e>=4 -> 32s+16+4g+(e-4).
__device__ __forceinline__ int kappa_j(int s, int g, int e) {
    return (e < 4) ? (32 * s + 4 * g + e) : (32 * s + 16 + 4 * g + e - 4);
}

// Combined prep: blocks 0..62 write per-lane fragment-ordered F16 weights into
// Afrag[l] (18432 B per l); blocks 63.. convert x -> xh (f16). Layout = R9's
// (verified), dtype bf16 -> f16.
__global__ __launch_bounds__(256) void prep_kernel(
    const float* __restrict__ x,
    const float* __restrict__ W1, const float* __restrict__ b1,
    const float* __restrict__ W2, const float* __restrict__ W3,
    unsigned short* __restrict__ Afrag,
    unsigned short* __restrict__ xh)
{
    const int t = threadIdx.x;
    const int b = blockIdx.x;
    if (b >= LN) {
        const int i = ((b - LN) * 256 + t) * 4;
        const float4 v = *reinterpret_cast<const float4*>(x + i);
        ushort4 o;
        o.x = f2h(v.x); o.y = f2h(v.y); o.z = f2h(v.z); o.w = f2h(v.w);
        *reinterpret_cast<ushort4*>(xh + i) = o;
        return;
    }
    const int l = b;
    unsigned short* Af = Afrag + (size_t)l * 9216;

    // A1: 512 items (s,tt,lane), 2 per thread
    #pragma unroll
    for (int it = 0; it < 2; ++it) {
        const int item = t + it * 256;
        const int s = item >> 8, tt = (item >> 6) & 3, lane = item & 63;
        const int g = lane >> 4, mcol = lane & 15, h = 16 * tt + mcol;
        unsigned pk[4];
        #pragma unroll
        for (int ep = 0; ep < 4; ++ep) {
            float v[2];
            #pragma unroll
            for (int k = 0; k < 2; ++k) {
                const int e = 2 * ep + k;
                const int j = 32 * s + 8 * g + e;
                float val;
                if (j == 63)      val = b1[l * 64 + h];
                else if (j <= l)  val = W1[(l * LN + j) * 64 + h];
                else              val = 0.0f;
                v[k] = val;
            }
            pk[ep] = pk2h(v[0], v[1]);
        }
        *reinterpret_cast<uint4*>(Af + ((size_t)item) * 8) =
            uint4{pk[0], pk[1], pk[2], pk[3]};
    }
    // A2: 512 items
    #pragma unroll
    for (int it = 0; it < 2; ++it) {
        const int item = t + it * 256;
        const int s = item >> 8, tt = (item >> 6) & 3, lane = item & 63;
        const int g = lane >> 4, mcol = lane & 15, h = 16 * tt + mcol;
        unsigned pk[4];
        #pragma unroll
        for (int ep = 0; ep < 4; ++ep) {
            float v[2];
            #pragma unroll
            for (int k = 0; k < 2; ++k) {
                const int e = 2 * ep + k;
                v[k] = W2[(l * 64 + kappa_j(s, g, e)) * 64 + h];
            }
            pk[ep] = pk2h(v[0], v[1]);
        }
        *reinterpret_cast<uint4*>(Af + 4096 + ((size_t)item) * 8) =
            uint4{pk[0], pk[1], pk[2], pk[3]};
    }
    // A3: 128 items (s,lane)
    if (t < 128) {
        const int s = t >> 6, lane = t & 63;
        const int g = lane >> 4, mcol = lane & 15;
        unsigned pk[4] = {0u, 0u, 0u, 0u};
        if (mcol < 2) {
            #pragma unroll
            for (int ep = 0; ep < 4; ++ep) {
                float v[2];
                #pragma unroll
                for (int k = 0; k < 2; ++k) {
                    const int e = 2 * ep + k;
                    v[k] = W3[(l * 64 + kappa_j(s, g, e)) * 2 + mcol];
                }
                pk[ep] = pk2h(v[0], v[1]);
            }
        }
        *reinterpret_cast<uint4*>(Af + 8192 + ((size_t)t) * 8) =
            uint4{pk[0], pk[1], pk[2], pk[3]};
    }
}

// Block = one l (0..62) x 1024 batch rows. Grid 63*16 = 1008. No LDS.
// R13/R14: issue-port attack. (a) all-f16 MFMA path (same fragment layout as
// the verified bf16 one); (b) tanh = packed-f16 Pade(5,4) -> 2 values/instr,
// cvt_pkrtz doubles as the pack, outputs assemble into B-fragments shuffle-
// free; (c) w1f hoisted (loop-invariant). Dual-chain structure from R12.
__global__ __launch_bounds__(256, 2) void maf_main_kernel(
    const float* __restrict__ x,
    const unsigned short* __restrict__ xh,
    const unsigned short* __restrict__ Afrag,
    const float* __restrict__ b2,
    const float* __restrict__ b3,
    float* __restrict__ zT,   // ws: [63][BATCH] row cr=62-l (z col l+1 reversed)
    float* __restrict__ aT)   // ws: [63][BATCH] alpha col l+1
{
    const int t = threadIdx.x;
    const int bid = blockIdx.x;
    const int l = bid % LN;                 // block-uniform
    const int rowBase = (bid / LN) * 1024;

    const int lane = t & 63;
    const int w = t >> 6;
    const int g = lane >> 4;
    const int mcol = lane & 15;

    // ---------------- persistent A-fragments (hoisted, incl. w1f) ----------
    const unsigned short* Af = Afrag + (size_t)l * 9216;
    f16x8 w1f[2][4], w2f[2][4], w3f[2];
    #pragma unroll
    for (int s = 0; s < 2; ++s) {
        #pragma unroll
        for (int tt = 0; tt < 4; ++tt) {
            w1f[s][tt] = *reinterpret_cast<const f16x8*>(Af + ((s * 4 + tt) * 64 + lane) * 8);
            w2f[s][tt] = *reinterpret_cast<const f16x8*>(Af + 4096 + ((s * 4 + tt) * 64 + lane) * 8);
        }
        w3f[s] = *reinterpret_cast<const f16x8*>(Af + 8192 + (s * 64 + lane) * 8);
    }
    f32x4 bias2[4];
    #pragma unroll
    for (int tt = 0; tt < 4; ++tt) {
        const float4 v2 = *reinterpret_cast<const float4*>(&b2[l * 64 + 16 * tt + 4 * g]);
        bias2[tt] = f32x4{v2.x, v2.y, v2.z, v2.w};
    }
    const float b30 = b3[l * 2 + 0];
    const float b31 = b3[l * 2 + 1];

    const int rowW = rowBase + w * 256 + mcol;
    const unsigned short* xrow = xh + (size_t)rowW * 64 + 8 * g;

    auto ldxf = [&](int k, f16x8& f0, f16x8& f1) {
        const unsigned short* p = xrow + (size_t)(16 * k) * 64;
        f0 = *reinterpret_cast<const f16x8*>(p);
        f1 = *reinterpret_cast<const f16x8*>(p + 32);
        if (g == 3) f1[7] = (_Float16)1.0f;   // b1 k-slot 63 pairs with 1.0
    };

    // prologue: prefetch groups 0 and 1
    f16x8 xa0, xa1, xb0, xb1, na0, na1, nb0, nb1;
    ldxf(0, xa0, xa1);
    ldxf(1, xb0, xb1);

    union U8 { h2 d[4]; f16x8 v; };

    // ---------------- 8 iterations x 2 row-groups ----------------
    #pragma unroll 1
    for (int it = 0; it < 8; ++it) {
        const int nk = (it < 7) ? (2 * it + 2) : 14;
        ldxf(nk, na0, na1);
        ldxf(nk + 1, nb0, nb1);

        // ---- layer 1, chains A/B interleaved (shared w1f) ----
        f32x4 c1a[4], c1b[4];
        #pragma unroll
        for (int tt = 0; tt < 4; ++tt) {
            c1a[tt] = f32x4{0.0f, 0.0f, 0.0f, 0.0f};
            c1b[tt] = f32x4{0.0f, 0.0f, 0.0f, 0.0f};
        }
        #pragma unroll
        for (int tt = 0; tt < 4; ++tt) {
            c1a[tt] = __builtin_amdgcn_mfma_f32_16x16x32_f16(w1f[0][tt], xa0, c1a[tt], 0, 0, 0);
            c1b[tt] = __builtin_amdgcn_mfma_f32_16x16x32_f16(w1f[0][tt], xb0, c1b[tt], 0, 0, 0);
        }
        #pragma unroll
        for (int tt = 0; tt < 4; ++tt) {
            c1a[tt] = __builtin_amdgcn_mfma_f32_16x16x32_f16(w1f[1][tt], xa1, c1a[tt], 0, 0, 0);
            c1b[tt] = __builtin_amdgcn_mfma_f32_16x16x32_f16(w1f[1][tt], xb1, c1b[tt], 0, 0, 0);
        }

        // ---- packed tanh + pack (zero-shuffle fragment assembly) ----
        f16x8 pfa[2], pfb[2];
        #pragma unroll
        for (int s = 0; s < 2; ++s) {
            U8 ua, ub;
            ua.d[0] = tanh_pk(c1a[2 * s][0], c1a[2 * s][1]);
            ub.d[0] = tanh_pk(c1b[2 * s][0], c1b[2 * s][1]);
            ua.d[1] = tanh_pk(c1a[2 * s][2], c1a[2 * s][3]);
            ub.d[1] = tanh_pk(c1b[2 * s][2], c1b[2 * s][3]);
            ua.d[2] = tanh_pk(c1a[2 * s + 1][0], c1a[2 * s + 1][1]);
            ub.d[2] = tanh_pk(c1b[2 * s + 1][0], c1b[2 * s + 1][1]);
            ua.d[3] = tanh_pk(c1a[2 * s + 1][2], c1a[2 * s + 1][3]);
            ub.d[3] = tanh_pk(c1b[2 * s + 1][2], c1b[2 * s + 1][3]);
            pfa[s] = ua.v;
            pfb[s] = ub.v;
        }

        // ---- layer 2, interleaved (shared w2f) ----
        f32x4 c2a[4], c2b[4];
        #pragma unroll
        for (int tt = 0; tt < 4; ++tt) { c2a[tt] = bias2[tt]; c2b[tt] = bias2[tt]; }
        #pragma unroll
        for (int s = 0; s < 2; ++s)
            #pragma unroll
            for (int tt = 0; tt < 4; ++tt) {
                c2a[tt] = __builtin_amdgcn_mfma_f32_16x16x32_f16(w2f[s][tt], pfa[s], c2a[tt], 0, 0, 0);
                c2b[tt] = __builtin_amdgcn_mfma_f32_16x16x32_f16(w2f[s][tt], pfb[s], c2b[tt], 0, 0, 0);
            }

        f16x8 qfa[2], qfb[2];
        #pragma unroll
        for (int s = 0; s < 2; ++s) {
            U8 ua, ub;
            ua.d[0] = tanh_pk(c2a[2 * s][0], c2a[2 * s][1]);
            ub.d[0] = tanh_pk(c2b[2 * s][0], c2b[2 * s][1]);
            ua.d[1] = tanh_pk(c2a[2 * s][2], c2a[2 * s][3]);
            ub.d[1] = tanh_pk(c2b[2 * s][2], c2b[2 * s][3]);
            ua.d[2] = tanh_pk(c2a[2 * s + 1][0], c2a[2 * s + 1][1]);
            ub.d[2] = tanh_pk(c2b[2 * s + 1][0], c2b[2 * s + 1][1]);
            ua.d[3] = tanh_pk(c2a[2 * s + 1][2], c2a[2 * s + 1][3]);
            ub.d[3] = tanh_pk(c2b[2 * s + 1][2], c2b[2 * s + 1][3]);
            qfa[s] = ua.v;
            qfb[s] = ub.v;
        }

        // ---- layer 3, interleaved (shared w3f) ----
        f32x4 c3a = {0.0f, 0.0f, 0.0f, 0.0f};
        f32x4 c3b = {0.0f, 0.0f, 0.0f, 0.0f};
        c3a = __builtin_amdgcn_mfma_f32_16x16x32_f16(w3f[0], qfa[0], c3a, 0, 0, 0);
        c3b = __builtin_amdgcn_mfma_f32_16x16x32_f16(w3f[0], qfb[0], c3b, 0, 0, 0);
        c3a = __builtin_amdgcn_mfma_f32_16x16x32_f16(w3f[1], qfa[1], c3a, 0, 0, 0);
        c3b = __builtin_amdgcn_mfma_f32_16x16x32_f16(w3f[1], qfb[1], c3b, 0, 0, 0);

        if (g == 0) {
            const int rowA = rowW + 32 * it;
            const int rowB = rowA + 16;
            const float muA = c3a[0] + b30, alA = c3a[1] + b31;
            const float muB = c3b[0] + b30, alB = c3b[1] + b31;
            const float xnA = x[(size_t)rowA * 64 + l + 1];
            const float xnB = x[(size_t)rowB * 64 + l + 1];
            zT[(62 - l) * BATCHN + rowA] = (xnA - muA) * fast_exp(-alA);
            zT[(62 - l) * BATCHN + rowB] = (xnB - muB) * fast_exp(-alB);
            aT[l * BATCHN + rowA] = alA;
            aT[l * BATCHN + rowB] = alB;
        }

        xa0 = na0; xa1 = na1; xb0 = nb0; xb1 = nb1;
    }
}

// 256 blocks x 64 rows: log_det + z col 0 + LDS transpose -> coalesced z_out.
__global__ __launch_bounds__(256) void maf_finish_kernel(
    const float* __restrict__ x,
    const float* __restrict__ ip,
    const float* __restrict__ zT,
    const float* __restrict__ aT,
    float* __restrict__ z_out,
    float* __restrict__ ld_out)
{
    __shared__ float tile[64][65];

    const int t = threadIdx.x;
    const int rb = blockIdx.x * 64;
    const float mu0 = ip[0];
    const float a0  = ip[1];
    const float e0  = fast_exp(-a0);

    // log_det: 4 lanes per row, shfl reduce
    {
        const int r = t >> 2, c = t & 3;
        const int row = rb + r;
        float s = 0.0f;
        for (int i = c; i < LN; i += 4) s += aT[(size_t)i * BATCHN + row];
        s += __shfl_xor(s, 1, 64);
        s += __shfl_xor(s, 2, 64);
        if (c == 0) ld_out[row] = -(s + a0);
    }

    // transpose 64 rows x 64 cols
    const int r = t & 63, cq = t >> 6;
    #pragma unroll
    for (int k = 0; k < 16; ++k) {
        const int c = cq * 16 + k;
        float v;
        if (c < 63) v = zT[(size_t)c * BATCHN + rb + r];
        else        v = (x[(size_t)(rb + r) * 64] - mu0) * e0;  // z col 0 -> cr 63
        tile[c][r] = v;
    }
    __syncthreads();
    #pragma unroll
    for (int i = 0; i < 16; ++i) {
        const int rr = cq * 16 + i;
        z_out[(size_t)(rb + rr) * 64 + r] = tile[r][rr];
    }
}

extern "C" void kernel_launch(void* const* d_in, const int* in_sizes, int n_in,
                              void* d_out, int out_size, void* d_ws, size_t ws_size,
                              hipStream_t stream) {
    const float* x  = (const float*)d_in[0];
    const float* ip = (const float*)d_in[1];
    const float* W1 = (const float*)d_in[2];
    const float* b1 = (const float*)d_in[3];
    const float* W2 = (const float*)d_in[4];
    const float* b2 = (const float*)d_in[5];
    const float* W3 = (const float*)d_in[6];
    const float* b3 = (const float*)d_in[7];

    float* z_out  = (float*)d_out;                     // [16384][64] (reversed cols)
    float* ld_out = z_out + (size_t)BATCHN * 64;       // [16384]

    // ws layout: Afrag [63*9216 u16 = 1.16MB] | zT 4.13MB | aT 4.13MB | xh 2MB
    unsigned short* Afrag = (unsigned short*)d_ws;
    float* zT = (float*)((char*)d_ws + (size_t)LN * 9216 * 2);
    float* aT = zT + (size_t)LN * BATCHN;
    unsigned short* xh = (unsigned short*)(aT + (size_t)LN * BATCHN);

    prep_kernel<<<dim3(LN + BATCHN * 64 / 1024), dim3(256), 0, stream>>>(
        x, W1, b1, W2, W3, Afrag, xh);
    maf_main_kernel<<<dim3(LN * 16), dim3(256), 0, stream>>>(
        x, xh, Afrag, b2, b3, zT, aT);
    maf_finish_kernel<<<dim3(BATCHN / 64), dim3(256), 0, stream>>>(
        x, ip, zT, aT, z_out, ld_out);
}

// Round 16
// 70.760 us; speedup vs baseline: 1.0029x; 1.0029x over previous
//
#include <hip/hip_runtime.h>

#define LN 63
#define BATCHN 16384

typedef __attribute__((ext_vector_type(8))) short bf16x8;   // 8 bf16 in 4 VGPRs
typedef __attribute__((ext_vector_type(4))) float f32x4;

__device__ __forceinline__ float fast_exp(float v) {
    return __builtin_amdgcn_exp2f(v * 1.4426950408889634f);
}
__device__ __forceinline__ float fast_tanh(float v) {
    float e = __builtin_amdgcn_exp2f(v * 2.8853900817779268f); // e^{2v}
    return 1.0f - 2.0f * __builtin_amdgcn_rcpf(e + 1.0f);
}
__device__ __forceinline__ short f2bf(float f) {
    __bf16 h = (__bf16)f;
    return __builtin_bit_cast(short, h);
}
__device__ __forceinline__ unsigned int pk2(float a, float b) {
    return (unsigned int)(unsigned short)f2bf(a) |
           ((unsigned int)(unsigned short)f2bf(b) << 16);
}

// kappa j-index for W2/W3 fragment element e (derived from R6's verified LDS
// reads): e<4 -> 32s+4g+e ; e>=4 -> 32s+16+4g+(e-4).
__device__ __forceinline__ int kappa_j(int s, int g, int e) {
    return (e < 4) ? (32 * s + 4 * g + e) : (32 * s + 16 + 4 * g + e - 4);
}

// Combined prep: blocks 0..62 write per-lane fragment-ordered bf16 weights
// into Afrag[l] (18432 B per l); blocks 63.. convert x -> xbf.  (R9-verified)
__global__ __launch_bounds__(256) void prep_kernel(
    const float* __restrict__ x,
    const float* __restrict__ W1, const float* __restrict__ b1,
    const float* __restrict__ W2, const float* __restrict__ W3,
    unsigned short* __restrict__ Afrag,
    unsigned short* __restrict__ xbf)
{
    const int t = threadIdx.x;
    const int b = blockIdx.x;
    if (b >= LN) {
        const int i = ((b - LN) * 256 + t) * 4;
        const float4 v = *reinterpret_cast<const float4*>(x + i);
        ushort4 o;
        o.x = (unsigned short)f2bf(v.x);
        o.y = (unsigned short)f2bf(v.y);
        o.z = (unsigned short)f2bf(v.z);
        o.w = (unsigned short)f2bf(v.w);
        *reinterpret_cast<ushort4*>(xbf + i) = o;
        return;
    }
    const int l = b;
    unsigned short* Af = Afrag + (size_t)l * 9216;

    // A1: 512 items (s,tt,lane), 2 per thread
    #pragma unroll
    for (int it = 0; it < 2; ++it) {
        const int item = t + it * 256;
        const int s = item >> 8, tt = (item >> 6) & 3, lane = item & 63;
        const int g = lane >> 4, mcol = lane & 15, h = 16 * tt + mcol;
        unsigned pk[4];
        #pragma unroll
        for (int ep = 0; ep < 4; ++ep) {
            float v[2];
            #pragma unroll
            for (int k = 0; k < 2; ++k) {
                const int e = 2 * ep + k;
                const int j = 32 * s + 8 * g + e;
                float val;
                if (j == 63)      val = b1[l * 64 + h];
                else if (j <= l)  val = W1[(l * LN + j) * 64 + h];
                else              val = 0.0f;
                v[k] = val;
            }
            pk[ep] = pk2(v[0], v[1]);
        }
        *reinterpret_cast<uint4*>(Af + ((size_t)item) * 8) =
            uint4{pk[0], pk[1], pk[2], pk[3]};
    }
    // A2: 512 items
    #pragma unroll
    for (int it = 0; it < 2; ++it) {
        const int item = t + it * 256;
        const int s = item >> 8, tt = (item >> 6) & 3, lane = item & 63;
        const int g = lane >> 4, mcol = lane & 15, h = 16 * tt + mcol;
        unsigned pk[4];
        #pragma unroll
        for (int ep = 0; ep < 4; ++ep) {
            float v[2];
            #pragma unroll
            for (int k = 0; k < 2; ++k) {
                const int e = 2 * ep + k;
                v[k] = W2[(l * 64 + kappa_j(s, g, e)) * 64 + h];
            }
            pk[ep] = pk2(v[0], v[1]);
        }
        *reinterpret_cast<uint4*>(Af + 4096 + ((size_t)item) * 8) =
            uint4{pk[0], pk[1], pk[2], pk[3]};
    }
    // A3: 128 items (s,lane)
    if (t < 128) {
        const int s = t >> 6, lane = t & 63;
        const int g = lane >> 4, mcol = lane & 15;
        unsigned pk[4] = {0u, 0u, 0u, 0u};
        if (mcol < 2) {
            #pragma unroll
            for (int ep = 0; ep < 4; ++ep) {
                float v[2];
                #pragma unroll
                for (int k = 0; k < 2; ++k) {
                    const int e = 2 * ep + k;
                    v[k] = W3[(l * 64 + kappa_j(s, g, e)) * 2 + mcol];
                }
                pk[ep] = pk2(v[0], v[1]);
            }
        }
        *reinterpret_cast<uint4*>(Af + 8192 + ((size_t)t) * 8) =
            uint4{pk[0], pk[1], pk[2], pk[3]};
    }
}

// Block = one l (0..62) x 1024 batch rows. Grid 63*16 = 1008. No LDS.
// R15: MINIMAL LIVE STATE. R12's post-mortem: occupancy ~27% => ~230 live
// regs/thread (occupancy ~= 512/total), far above source-level estimate; the
// excess is persistent-fragment arrays (likely AGPR-mirrored MFMA operands).
// Fix: NOTHING persistent but bias2 — every weight fragment (w1f/w2f/w3f) is
// re-loaded per grp from the fragment-ordered Afrag (L1-hot: same 18 lines
// each grp). Single chain. Peak live ~90 -> natural allocation should admit
// 4-6 waves/SIMD. Math identical to R9/R12 (verified absmax 0.0625).
__global__ __launch_bounds__(256) void maf_main_kernel(
    const float* __restrict__ x,
    const unsigned short* __restrict__ xbf,
    const unsigned short* __restrict__ Afrag,
    const float* __restrict__ b2,
    const float* __restrict__ b3,
    float* __restrict__ zT,   // ws: [63][BATCH] row cr=62-l (z col l+1 reversed)
    float* __restrict__ aT)   // ws: [63][BATCH] alpha col l+1
{
    const int t = threadIdx.x;
    const int bid = blockIdx.x;
    const int l = bid % LN;                 // block-uniform
    const int rowBase = (bid / LN) * 1024;

    const int lane = t & 63;
    const int w = t >> 6;
    const int g = lane >> 4;
    const int mcol = lane & 15;

    const unsigned short* Af = Afrag + (size_t)l * 9216;
    const unsigned short* Af1 = Af + lane * 8;           // w1f base (per-lane)
    const unsigned short* Af2 = Af + 4096 + lane * 8;    // w2f base
    const unsigned short* Af3 = Af + 8192 + lane * 8;    // w3f base

    f32x4 bias2[4];
    #pragma unroll
    for (int tt = 0; tt < 4; ++tt) {
        const float4 v2 = *reinterpret_cast<const float4*>(&b2[l * 64 + 16 * tt + 4 * g]);
        bias2[tt] = f32x4{v2.x, v2.y, v2.z, v2.w};
    }
    const float b30 = b3[l * 2 + 0];
    const float b31 = b3[l * 2 + 1];
    const short one_bf = (short)0x3F80;   // bf16(1.0)

    const int rowW = rowBase + w * 256 + mcol;
    const unsigned short* xrow = xbf + (size_t)rowW * 64 + 8 * g;

    // ---------------- 16 groups of 16 rows per wave ----------------
    #pragma unroll 1
    for (int grp = 0; grp < 16; ++grp) {
        const unsigned short* xp = xrow + (size_t)(16 * grp) * 64;

        bf16x8 xf0 = *reinterpret_cast<const bf16x8*>(xp);
        bf16x8 xf1 = *reinterpret_cast<const bf16x8*>(xp + 32);
        if (g == 3) xf1[7] = one_bf;   // b1 k-slot 63 pairs with 1.0

        // ---- layer 1: w1f loaded fresh (L1-hot), c1 = 16 regs ----
        f32x4 c1[4];
        #pragma unroll
        for (int tt = 0; tt < 4; ++tt) {
            const bf16x8 wa = *reinterpret_cast<const bf16x8*>(Af1 + (0 * 4 + tt) * 512);
            c1[tt] = __builtin_amdgcn_mfma_f32_16x16x32_bf16(
                wa, xf0, f32x4{0.0f, 0.0f, 0.0f, 0.0f}, 0, 0, 0);
        }
        #pragma unroll
        for (int tt = 0; tt < 4; ++tt) {
            const bf16x8 wa = *reinterpret_cast<const bf16x8*>(Af1 + (1 * 4 + tt) * 512);
            c1[tt] = __builtin_amdgcn_mfma_f32_16x16x32_bf16(wa, xf1, c1[tt], 0, 0, 0);
        }

        // ---- tanh + pack ----
        bf16x8 pf0, pf1;
        #pragma unroll
        for (int q = 0; q < 4; ++q) {
            pf0[q]     = f2bf(fast_tanh(c1[0][q]));
            pf0[4 + q] = f2bf(fast_tanh(c1[1][q]));
            pf1[q]     = f2bf(fast_tanh(c1[2][q]));
            pf1[4 + q] = f2bf(fast_tanh(c1[3][q]));
        }

        // ---- layer 2: w2f loaded fresh ----
        f32x4 c2[4];
        #pragma unroll
        for (int tt = 0; tt < 4; ++tt) {
            const bf16x8 wa = *reinterpret_cast<const bf16x8*>(Af2 + (0 * 4 + tt) * 512);
            c2[tt] = __builtin_amdgcn_mfma_f32_16x16x32_bf16(wa, pf0, bias2[tt], 0, 0, 0);
        }
        #pragma unroll
        for (int tt = 0; tt < 4; ++tt) {
            const bf16x8 wa = *reinterpret_cast<const bf16x8*>(Af2 + (1 * 4 + tt) * 512);
            c2[tt] = __builtin_amdgcn_mfma_f32_16x16x32_bf16(wa, pf1, c2[tt], 0, 0, 0);
        }

        bf16x8 qf0, qf1;
        #pragma unroll
        for (int q = 0; q < 4; ++q) {
            qf0[q]     = f2bf(fast_tanh(c2[0][q]));
            qf0[4 + q] = f2bf(fast_tanh(c2[1][q]));
            qf1[q]     = f2bf(fast_tanh(c2[2][q]));
            qf1[4 + q] = f2bf(fast_tanh(c2[3][q]));
        }

        // ---- layer 3: w3f loaded fresh ----
        const bf16x8 w30 = *reinterpret_cast<const bf16x8*>(Af3);
        const bf16x8 w31 = *reinterpret_cast<const bf16x8*>(Af3 + 512);
        f32x4 c3 = {0.0f, 0.0f, 0.0f, 0.0f};
        c3 = __builtin_amdgcn_mfma_f32_16x16x32_bf16(w30, qf0, c3, 0, 0, 0);
        c3 = __builtin_amdgcn_mfma_f32_16x16x32_bf16(w31, qf1, c3, 0, 0, 0);

        if (g == 0) {
            const int row = rowW + 16 * grp;
            const float mu = c3[0] + b30;
            const float al = c3[1] + b31;
            const float xn = x[(size_t)row * 64 + l + 1];   // f32 input
            const float zv = (xn - mu) * fast_exp(-al);
            zT[(62 - l) * BATCHN + row] = zv;
            aT[l * BATCHN + row] = al;
        }
    }
}

// 256 blocks x 64 rows: log_det + z col 0 + LDS transpose -> coalesced z_out.
__global__ __launch_bounds__(256) void maf_finish_kernel(
    const float* __restrict__ x,
    const float* __restrict__ ip,
    const float* __restrict__ zT,
    const float* __restrict__ aT,
    float* __restrict__ z_out,
    float* __restrict__ ld_out)
{
    __shared__ float tile[64][65];

    const int t = threadIdx.x;
    const int rb = blockIdx.x * 64;
    const float mu0 = ip[0];
    const float a0  = ip[1];
    const float e0  = fast_exp(-a0);

    // log_det: 4 lanes per row, shfl reduce
    {
        const int r = t >> 2, c = t & 3;
        const int row = rb + r;
        float s = 0.0f;
        for (int i = c; i < LN; i += 4) s += aT[(size_t)i * BATCHN + row];
        s += __shfl_xor(s, 1, 64);
        s += __shfl_xor(s, 2, 64);
        if (c == 0) ld_out[row] = -(s + a0);
    }

    // transpose 64 rows x 64 cols
    const int r = t & 63, cq = t >> 6;
    #pragma unroll
    for (int k = 0; k < 16; ++k) {
        const int c = cq * 16 + k;
        float v;
        if (c < 63) v = zT[(size_t)c * BATCHN + rb + r];
        else        v = (x[(size_t)(rb + r) * 64] - mu0) * e0;  // z col 0 -> cr 63
        tile[c][r] = v;
    }
    __syncthreads();
    #pragma unroll
    for (int i = 0; i < 16; ++i) {
        const int rr = cq * 16 + i;
        z_out[(size_t)(rb + rr) * 64 + r] = tile[r][rr];
    }
}

extern "C" void kernel_launch(void* const* d_in, const int* in_sizes, int n_in,
                              void* d_out, int out_size, void* d_ws, size_t ws_size,
                              hipStream_t stream) {
    const float* x  = (const float*)d_in[0];
    const float* ip = (const float*)d_in[1];
    const float* W1 = (const float*)d_in[2];
    const float* b1 = (const float*)d_in[3];
    const float* W2 = (const float*)d_in[4];
    const float* b2 = (const float*)d_in[5];
    const float* W3 = (const float*)d_in[6];
    const float* b3 = (const float*)d_in[7];

    float* z_out  = (float*)d_out;                     // [16384][64] (reversed cols)
    float* ld_out = z_out + (size_t)BATCHN * 64;       // [16384]

    // ws layout: Afrag [63*9216 u16 = 1.16MB] | zT 4.13MB | aT 4.13MB | xbf 2MB
    unsigned short* Afrag = (unsigned short*)d_ws;
    float* zT = (float*)((char*)d_ws + (size_t)LN * 9216 * 2);
    float* aT = zT + (size_t)LN * BATCHN;
    unsigned short* xbf = (unsigned short*)(aT + (size_t)LN * BATCHN);

    prep_kernel<<<dim3(LN + BATCHN * 64 / 1024), dim3(256), 0, stream>>>(
        x, W1, b1, W2, W3, Afrag, xbf);
    maf_main_kernel<<<dim3(LN * 16), dim3(256), 0, stream>>>(
        x, xbf, Afrag, b2, b3, zT, aT);
    maf_finish_kernel<<<dim3(BATCHN / 64), dim3(256), 0, stream>>>(
        x, ip, zT, aT, z_out, ld_out);
}

// Round 17
// 70.696 us; speedup vs baseline: 1.0038x; 1.0009x over previous
//
#include <hip/hip_runtime.h>

#define LN 63
#define BATCHN 16384

typedef __attribute__((ext_vector_type(8))) short bf16x8;   // 8 bf16 in 4 VGPRs
typedef __attribute__((ext_vector_type(4))) float f32x4;

__device__ __forceinline__ float fast_exp(float v) {
    return __builtin_amdgcn_exp2f(v * 1.4426950408889634f);
}
__device__ __forceinline__ float fast_tanh(float v) {
    float e = __builtin_amdgcn_exp2f(v * 2.8853900817779268f); // e^{2v}
    return 1.0f - 2.0f * __builtin_amdgcn_rcpf(e + 1.0f);
}
__device__ __forceinline__ short f2bf(float f) {
    __bf16 h = (__bf16)f;
    return __builtin_bit_cast(short, h);
}
__device__ __forceinline__ unsigned int pk2(float a, float b) {
    return (unsigned int)(unsigned short)f2bf(a) |
           ((unsigned int)(unsigned short)f2bf(b) << 16);
}

// kappa j-index for W2/W3 fragment element e (derived from R6's verified LDS
// reads): e<4 -> 32s+4g+e ; e>=4 -> 32s+16+4g+(e-4).
__device__ __forceinline__ int kappa_j(int s, int g, int e) {
    return (e < 4) ? (32 * s + 4 * g + e) : (32 * s + 16 + 4 * g + e - 4);
}

// Combined prep: blocks 0..62 write per-lane fragment-ordered bf16 weights
// into Afrag[l] (18432 B per l); blocks 63.. convert x -> xbf.  (R9-verified)
__global__ __launch_bounds__(256) void prep_kernel(
    const float* __restrict__ x,
    const float* __restrict__ W1, const float* __restrict__ b1,
    const float* __restrict__ W2, const float* __restrict__ W3,
    unsigned short* __restrict__ Afrag,
    unsigned short* __restrict__ xbf)
{
    const int t = threadIdx.x;
    const int b = blockIdx.x;
    if (b >= LN) {
        const int i = ((b - LN) * 256 + t) * 4;
        const float4 v = *reinterpret_cast<const float4*>(x + i);
        ushort4 o;
        o.x = (unsigned short)f2bf(v.x);
        o.y = (unsigned short)f2bf(v.y);
        o.z = (unsigned short)f2bf(v.z);
        o.w = (unsigned short)f2bf(v.w);
        *reinterpret_cast<ushort4*>(xbf + i) = o;
        return;
    }
    const int l = b;
    unsigned short* Af = Afrag + (size_t)l * 9216;

    // A1: 512 items (s,tt,lane), 2 per thread
    #pragma unroll
    for (int it = 0; it < 2; ++it) {
        const int item = t + it * 256;
        const int s = item >> 8, tt = (item >> 6) & 3, lane = item & 63;
        const int g = lane >> 4, mcol = lane & 15, h = 16 * tt + mcol;
        unsigned pk[4];
        #pragma unroll
        for (int ep = 0; ep < 4; ++ep) {
            float v[2];
            #pragma unroll
            for (int k = 0; k < 2; ++k) {
                const int e = 2 * ep + k;
                const int j = 32 * s + 8 * g + e;
                float val;
                if (j == 63)      val = b1[l * 64 + h];
                else if (j <= l)  val = W1[(l * LN + j) * 64 + h];
                else              val = 0.0f;
                v[k] = val;
            }
            pk[ep] = pk2(v[0], v[1]);
        }
        *reinterpret_cast<uint4*>(Af + ((size_t)item) * 8) =
            uint4{pk[0], pk[1], pk[2], pk[3]};
    }
    // A2: 512 items
    #pragma unroll
    for (int it = 0; it < 2; ++it) {
        const int item = t + it * 256;
        const int s = item >> 8, tt = (item >> 6) & 3, lane = item & 63;
        const int g = lane >> 4, mcol = lane & 15, h = 16 * tt + mcol;
        unsigned pk[4];
        #pragma unroll
        for (int ep = 0; ep < 4; ++ep) {
            float v[2];
            #pragma unroll
            for (int k = 0; k < 2; ++k) {
                const int e = 2 * ep + k;
                v[k] = W2[(l * 64 + kappa_j(s, g, e)) * 64 + h];
            }
            pk[ep] = pk2(v[0], v[1]);
        }
        *reinterpret_cast<uint4*>(Af + 4096 + ((size_t)item) * 8) =
            uint4{pk[0], pk[1], pk[2], pk[3]};
    }
    // A3: 128 items (s,lane)
    if (t < 128) {
        const int s = t >> 6, lane = t & 63;
        const int g = lane >> 4, mcol = lane & 15;
        unsigned pk[4] = {0u, 0u, 0u, 0u};
        if (mcol < 2) {
            #pragma unroll
            for (int ep = 0; ep < 4; ++ep) {
                float v[2];
                #pragma unroll
                for (int k = 0; k < 2; ++k) {
                    const int e = 2 * ep + k;
                    v[k] = W3[(l * 64 + kappa_j(s, g, e)) * 2 + mcol];
                }
                pk[ep] = pk2(v[0], v[1]);
            }
        }
        *reinterpret_cast<uint4*>(Af + 8192 + ((size_t)t) * 8) =
            uint4{pk[0], pk[1], pk[2], pk[3]};
    }
}

// Block = one l (0..62) x 256 batch rows. Grid 63*64 = 4032 (~15.75/CU
// available; VGPR~68 -> ~7 waves/SIMD ceiling). R16: R15's staging-free
// minimal-live-state structure with 4x the grid — per-block prologue is only
// bias2+addressing (~30 instr), so small blocks are nearly free, and resident
// waves/SIMD should finally rise (the lever R3-R15 never delivered).
// Math identical to R9/R12/R15 (verified absmax 0.0625).
__global__ __launch_bounds__(256) void maf_main_kernel(
    const float* __restrict__ x,
    const unsigned short* __restrict__ xbf,
    const unsigned short* __restrict__ Afrag,
    const float* __restrict__ b2,
    const float* __restrict__ b3,
    float* __restrict__ zT,   // ws: [63][BATCH] row cr=62-l (z col l+1 reversed)
    float* __restrict__ aT)   // ws: [63][BATCH] alpha col l+1
{
    const int t = threadIdx.x;
    const int bid = blockIdx.x;
    const int l = bid % LN;                 // block-uniform
    const int rowBase = (bid / LN) * 256;

    const int lane = t & 63;
    const int w = t >> 6;
    const int g = lane >> 4;
    const int mcol = lane & 15;

    const unsigned short* Af = Afrag + (size_t)l * 9216;
    const unsigned short* Af1 = Af + lane * 8;           // w1f base (per-lane)
    const unsigned short* Af2 = Af + 4096 + lane * 8;    // w2f base
    const unsigned short* Af3 = Af + 8192 + lane * 8;    // w3f base

    f32x4 bias2[4];
    #pragma unroll
    for (int tt = 0; tt < 4; ++tt) {
        const float4 v2 = *reinterpret_cast<const float4*>(&b2[l * 64 + 16 * tt + 4 * g]);
        bias2[tt] = f32x4{v2.x, v2.y, v2.z, v2.w};
    }
    const float b30 = b3[l * 2 + 0];
    const float b31 = b3[l * 2 + 1];
    const short one_bf = (short)0x3F80;   // bf16(1.0)

    const int rowW = rowBase + w * 64 + mcol;
    const unsigned short* xrow = xbf + (size_t)rowW * 64 + 8 * g;

    // ---------------- 4 groups of 16 rows per wave ----------------
    #pragma unroll 1
    for (int grp = 0; grp < 4; ++grp) {
        const unsigned short* xp = xrow + (size_t)(16 * grp) * 64;

        bf16x8 xf0 = *reinterpret_cast<const bf16x8*>(xp);
        bf16x8 xf1 = *reinterpret_cast<const bf16x8*>(xp + 32);
        if (g == 3) xf1[7] = one_bf;   // b1 k-slot 63 pairs with 1.0

        // ---- layer 1: w1f loaded fresh (L1/L2-hot), c1 = 16 regs ----
        f32x4 c1[4];
        #pragma unroll
        for (int tt = 0; tt < 4; ++tt) {
            const bf16x8 wa = *reinterpret_cast<const bf16x8*>(Af1 + (0 * 4 + tt) * 512);
            c1[tt] = __builtin_amdgcn_mfma_f32_16x16x32_bf16(
                wa, xf0, f32x4{0.0f, 0.0f, 0.0f, 0.0f}, 0, 0, 0);
        }
        #pragma unroll
        for (int tt = 0; tt < 4; ++tt) {
            const bf16x8 wa = *reinterpret_cast<const bf16x8*>(Af1 + (1 * 4 + tt) * 512);
            c1[tt] = __builtin_amdgcn_mfma_f32_16x16x32_bf16(wa, xf1, c1[tt], 0, 0, 0);
        }

        // ---- tanh + pack ----
        bf16x8 pf0, pf1;
        #pragma unroll
        for (int q = 0; q < 4; ++q) {
            pf0[q]     = f2bf(fast_tanh(c1[0][q]));
            pf0[4 + q] = f2bf(fast_tanh(c1[1][q]));
            pf1[q]     = f2bf(fast_tanh(c1[2][q]));
            pf1[4 + q] = f2bf(fast_tanh(c1[3][q]));
        }

        // ---- layer 2: w2f loaded fresh ----
        f32x4 c2[4];
        #pragma unroll
        for (int tt = 0; tt < 4; ++tt) {
            const bf16x8 wa = *reinterpret_cast<const bf16x8*>(Af2 + (0 * 4 + tt) * 512);
            c2[tt] = __builtin_amdgcn_mfma_f32_16x16x32_bf16(wa, pf0, bias2[tt], 0, 0, 0);
        }
        #pragma unroll
        for (int tt = 0; tt < 4; ++tt) {
            const bf16x8 wa = *reinterpret_cast<const bf16x8*>(Af2 + (1 * 4 + tt) * 512);
            c2[tt] = __builtin_amdgcn_mfma_f32_16x16x32_bf16(wa, pf1, c2[tt], 0, 0, 0);
        }

        bf16x8 qf0, qf1;
        #pragma unroll
        for (int q = 0; q < 4; ++q) {
            qf0[q]     = f2bf(fast_tanh(c2[0][q]));
            qf0[4 + q] = f2bf(fast_tanh(c2[1][q]));
            qf1[q]     = f2bf(fast_tanh(c2[2][q]));
            qf1[4 + q] = f2bf(fast_tanh(c2[3][q]));
        }

        // ---- layer 3: w3f loaded fresh ----
        const bf16x8 w30 = *reinterpret_cast<const bf16x8*>(Af3);
        const bf16x8 w31 = *reinterpret_cast<const bf16x8*>(Af3 + 512);
        f32x4 c3 = {0.0f, 0.0f, 0.0f, 0.0f};
        c3 = __builtin_amdgcn_mfma_f32_16x16x32_bf16(w30, qf0, c3, 0, 0, 0);
        c3 = __builtin_amdgcn_mfma_f32_16x16x32_bf16(w31, qf1, c3, 0, 0, 0);

        if (g == 0) {
            const int row = rowW + 16 * grp;
            const float mu = c3[0] + b30;
            const float al = c3[1] + b31;
            const float xn = x[(size_t)row * 64 + l + 1];   // f32 input
            const float zv = (xn - mu) * fast_exp(-al);
            zT[(62 - l) * BATCHN + row] = zv;
            aT[l * BATCHN + row] = al;
        }
    }
}

// 256 blocks x 64 rows: log_det + z col 0 + LDS transpose -> coalesced z_out.
__global__ __launch_bounds__(256) void maf_finish_kernel(
    const float* __restrict__ x,
    const float* __restrict__ ip,
    const float* __restrict__ zT,
    const float* __restrict__ aT,
    float* __restrict__ z_out,
    float* __restrict__ ld_out)
{
    __shared__ float tile[64][65];

    const int t = threadIdx.x;
    const int rb = blockIdx.x * 64;
    const float mu0 = ip[0];
    const float a0  = ip[1];
    const float e0  = fast_exp(-a0);

    // log_det: 4 lanes per row, shfl reduce
    {
        const int r = t >> 2, c = t & 3;
        const int row = rb + r;
        float s = 0.0f;
        for (int i = c; i < LN; i += 4) s += aT[(size_t)i * BATCHN + row];
        s += __shfl_xor(s, 1, 64);
        s += __shfl_xor(s, 2, 64);
        if (c == 0) ld_out[row] = -(s + a0);
    }

    // transpose 64 rows x 64 cols
    const int r = t & 63, cq = t >> 6;
    #pragma unroll
    for (int k = 0; k < 16; ++k) {
        const int c = cq * 16 + k;
        float v;
        if (c < 63) v = zT[(size_t)c * BATCHN + rb + r];
        else        v = (x[(size_t)(rb + r) * 64] - mu0) * e0;  // z col 0 -> cr 63
        tile[c][r] = v;
    }
    __syncthreads();
    #pragma unroll
    for (int i = 0; i < 16; ++i) {
        const int rr = cq * 16 + i;
        z_out[(size_t)(rb + rr) * 64 + r] = tile[r][rr];
    }
}

extern "C" void kernel_launch(void* const* d_in, const int* in_sizes, int n_in,
                              void* d_out, int out_size, void* d_ws, size_t ws_size,
                              hipStream_t stream) {
    const float* x  = (const float*)d_in[0];
    const float* ip = (const float*)d_in[1];
    const float* W1 = (const float*)d_in[2];
    const float* b1 = (const float*)d_in[3];
    const float* W2 = (const float*)d_in[4];
    const float* b2 = (const float*)d_in[5];
    const float* W3 = (const float*)d_in[6];
    const float* b3 = (const float*)d_in[7];

    float* z_out  = (float*)d_out;                     // [16384][64] (reversed cols)
    float* ld_out = z_out + (size_t)BATCHN * 64;       // [16384]

    // ws layout: Afrag [63*9216 u16 = 1.16MB] | zT 4.13MB | aT 4.13MB | xbf 2MB
    unsigned short* Afrag = (unsigned short*)d_ws;
    float* zT = (float*)((char*)d_ws + (size_t)LN * 9216 * 2);
    float* aT = zT + (size_t)LN * BATCHN;
    unsigned short* xbf = (unsigned short*)(aT + (size_t)LN * BATCHN);

    prep_kernel<<<dim3(LN + BATCHN * 64 / 1024), dim3(256), 0, stream>>>(
        x, W1, b1, W2, W3, Afrag, xbf);
    maf_main_kernel<<<dim3(LN * 64), dim3(256), 0, stream>>>(
        x, xbf, Afrag, b2, b3, zT, aT);
    maf_finish_kernel<<<dim3(BATCHN / 64), dim3(256), 0, stream>>>(
        x, ip, zT, aT, z_out, ld_out);
}

// Round 18
// 68.425 us; speedup vs baseline: 1.0371x; 1.0332x over previous
//
#include <hip/hip_runtime.h>

#define LN 63
#define BATCHN 16384

typedef __attribute__((ext_vector_type(8))) short bf16x8;   // 8 bf16 in 4 VGPRs
typedef __attribute__((ext_vector_type(4))) float f32x4;

__device__ __forceinline__ float fast_exp(float v) {
    return __builtin_amdgcn_exp2f(v * 1.4426950408889634f);
}
__device__ __forceinline__ float fast_tanh(float v) {
    float e = __builtin_amdgcn_exp2f(v * 2.8853900817779268f); // e^{2v}
    return 1.0f - 2.0f * __builtin_amdgcn_rcpf(e + 1.0f);
}
__device__ __forceinline__ short f2bf(float f) {
    __bf16 h = (__bf16)f;
    return __builtin_bit_cast(short, h);
}
__device__ __forceinline__ unsigned int pk2(float a, float b) {
    return (unsigned int)(unsigned short)f2bf(a) |
           ((unsigned int)(unsigned short)f2bf(b) << 16);
}

// kappa j-index for W2/W3 fragment element e (derived from R6's verified LDS
// reads): e<4 -> 32s+4g+e ; e>=4 -> 32s+16+4g+(e-4).
__device__ __forceinline__ int kappa_j(int s, int g, int e) {
    return (e < 4) ? (32 * s + 4 * g + e) : (32 * s + 16 + 4 * g + e - 4);
}

// Combined prep: blocks 0..62 write per-lane fragment-ordered bf16 weights
// into Afrag[l] (18432 B per l); blocks 63.. convert x -> xbf.  (R9-verified)
__global__ __launch_bounds__(256) void prep_kernel(
    const float* __restrict__ x,
    const float* __restrict__ W1, const float* __restrict__ b1,
    const float* __restrict__ W2, const float* __restrict__ W3,
    unsigned short* __restrict__ Afrag,
    unsigned short* __restrict__ xbf)
{
    const int t = threadIdx.x;
    const int b = blockIdx.x;
    if (b >= LN) {
        const int i = ((b - LN) * 256 + t) * 4;
        const float4 v = *reinterpret_cast<const float4*>(x + i);
        ushort4 o;
        o.x = (unsigned short)f2bf(v.x);
        o.y = (unsigned short)f2bf(v.y);
        o.z = (unsigned short)f2bf(v.z);
        o.w = (unsigned short)f2bf(v.w);
        *reinterpret_cast<ushort4*>(xbf + i) = o;
        return;
    }
    const int l = b;
    unsigned short* Af = Afrag + (size_t)l * 9216;

    // A1: 512 items (s,tt,lane), 2 per thread
    #pragma unroll
    for (int it = 0; it < 2; ++it) {
        const int item = t + it * 256;
        const int s = item >> 8, tt = (item >> 6) & 3, lane = item & 63;
        const int g = lane >> 4, mcol = lane & 15, h = 16 * tt + mcol;
        unsigned pk[4];
        #pragma unroll
        for (int ep = 0; ep < 4; ++ep) {
            float v[2];
            #pragma unroll
            for (int k = 0; k < 2; ++k) {
                const int e = 2 * ep + k;
                const int j = 32 * s + 8 * g + e;
                float val;
                if (j == 63)      val = b1[l * 64 + h];
                else if (j <= l)  val = W1[(l * LN + j) * 64 + h];
                else              val = 0.0f;
                v[k] = val;
            }
            pk[ep] = pk2(v[0], v[1]);
        }
        *reinterpret_cast<uint4*>(Af + ((size_t)item) * 8) =
            uint4{pk[0], pk[1], pk[2], pk[3]};
    }
    // A2: 512 items
    #pragma unroll
    for (int it = 0; it < 2; ++it) {
        const int item = t + it * 256;
        const int s = item >> 8, tt = (item >> 6) & 3, lane = item & 63;
        const int g = lane >> 4, mcol = lane & 15, h = 16 * tt + mcol;
        unsigned pk[4];
        #pragma unroll
        for (int ep = 0; ep < 4; ++ep) {
            float v[2];
            #pragma unroll
            for (int k = 0; k < 2; ++k) {
                const int e = 2 * ep + k;
                v[k] = W2[(l * 64 + kappa_j(s, g, e)) * 64 + h];
            }
            pk[ep] = pk2(v[0], v[1]);
        }
        *reinterpret_cast<uint4*>(Af + 4096 + ((size_t)item) * 8) =
            uint4{pk[0], pk[1], pk[2], pk[3]};
    }
    // A3: 128 items (s,lane)
    if (t < 128) {
        const int s = t >> 6, lane = t & 63;
        const int g = lane >> 4, mcol = lane & 15;
        unsigned pk[4] = {0u, 0u, 0u, 0u};
        if (mcol < 2) {
            #pragma unroll
            for (int ep = 0; ep < 4; ++ep) {
                float v[2];
                #pragma unroll
                for (int k = 0; k < 2; ++k) {
                    const int e = 2 * ep + k;
                    v[k] = W3[(l * 64 + kappa_j(s, g, e)) * 2 + mcol];
                }
                pk[ep] = pk2(v[0], v[1]);
            }
        }
        *reinterpret_cast<uint4*>(Af + 8192 + ((size_t)t) * 8) =
            uint4{pk[0], pk[1], pk[2], pk[3]};
    }
}

// Block = ONE WAVE (64 threads) x one l x 64 batch rows. Grid 63*256 = 16128.
// R17: wave-granular residency probe. All prior variants used 4-wave blocks
// and sat at ~2.1 waves/SIMD resident; if the binder is per-BLOCK admission
// (4 waves co-allocated against a ~240-reg/wave actual allocation), 1-wave
// blocks let the dispatcher pack waves individually. Inner math = R15/R16
// (verified absmax 0.0625); per-block prologue ~30 instr, so 4x more blocks
// is ~free.
__global__ __launch_bounds__(64) void maf_main_kernel(
    const float* __restrict__ x,
    const unsigned short* __restrict__ xbf,
    const unsigned short* __restrict__ Afrag,
    const float* __restrict__ b2,
    const float* __restrict__ b3,
    float* __restrict__ zT,   // ws: [63][BATCH] row cr=62-l (z col l+1 reversed)
    float* __restrict__ aT)   // ws: [63][BATCH] alpha col l+1
{
    const int lane = threadIdx.x;           // 0..63
    const int bid = blockIdx.x;
    const int l = bid % LN;                 // block-uniform
    const int rowBase = (bid / LN) * 64;

    const int g = lane >> 4;
    const int mcol = lane & 15;

    const unsigned short* Af = Afrag + (size_t)l * 9216;
    const unsigned short* Af1 = Af + lane * 8;           // w1f base (per-lane)
    const unsigned short* Af2 = Af + 4096 + lane * 8;    // w2f base
    const unsigned short* Af3 = Af + 8192 + lane * 8;    // w3f base

    f32x4 bias2[4];
    #pragma unroll
    for (int tt = 0; tt < 4; ++tt) {
        const float4 v2 = *reinterpret_cast<const float4*>(&b2[l * 64 + 16 * tt + 4 * g]);
        bias2[tt] = f32x4{v2.x, v2.y, v2.z, v2.w};
    }
    const float b30 = b3[l * 2 + 0];
    const float b31 = b3[l * 2 + 1];
    const short one_bf = (short)0x3F80;   // bf16(1.0)

    const int rowW = rowBase + mcol;
    const unsigned short* xrow = xbf + (size_t)rowW * 64 + 8 * g;

    // ---------------- 4 groups of 16 rows ----------------
    #pragma unroll 1
    for (int grp = 0; grp < 4; ++grp) {
        const unsigned short* xp = xrow + (size_t)(16 * grp) * 64;

        bf16x8 xf0 = *reinterpret_cast<const bf16x8*>(xp);
        bf16x8 xf1 = *reinterpret_cast<const bf16x8*>(xp + 32);
        if (g == 3) xf1[7] = one_bf;   // b1 k-slot 63 pairs with 1.0

        // ---- layer 1: w1f loaded fresh (L1/L2-hot) ----
        f32x4 c1[4];
        #pragma unroll
        for (int tt = 0; tt < 4; ++tt) {
            const bf16x8 wa = *reinterpret_cast<const bf16x8*>(Af1 + (0 * 4 + tt) * 512);
            c1[tt] = __builtin_amdgcn_mfma_f32_16x16x32_bf16(
                wa, xf0, f32x4{0.0f, 0.0f, 0.0f, 0.0f}, 0, 0, 0);
        }
        #pragma unroll
        for (int tt = 0; tt < 4; ++tt) {
            const bf16x8 wa = *reinterpret_cast<const bf16x8*>(Af1 + (1 * 4 + tt) * 512);
            c1[tt] = __builtin_amdgcn_mfma_f32_16x16x32_bf16(wa, xf1, c1[tt], 0, 0, 0);
        }

        // ---- tanh + pack ----
        bf16x8 pf0, pf1;
        #pragma unroll
        for (int q = 0; q < 4; ++q) {
            pf0[q]     = f2bf(fast_tanh(c1[0][q]));
            pf0[4 + q] = f2bf(fast_tanh(c1[1][q]));
            pf1[q]     = f2bf(fast_tanh(c1[2][q]));
            pf1[4 + q] = f2bf(fast_tanh(c1[3][q]));
        }

        // ---- layer 2: w2f loaded fresh ----
        f32x4 c2[4];
        #pragma unroll
        for (int tt = 0; tt < 4; ++tt) {
            const bf16x8 wa = *reinterpret_cast<const bf16x8*>(Af2 + (0 * 4 + tt) * 512);
            c2[tt] = __builtin_amdgcn_mfma_f32_16x16x32_bf16(wa, pf0, bias2[tt], 0, 0, 0);
        }
        #pragma unroll
        for (int tt = 0; tt < 4; ++tt) {
            const bf16x8 wa = *reinterpret_cast<const bf16x8*>(Af2 + (1 * 4 + tt) * 512);
            c2[tt] = __builtin_amdgcn_mfma_f32_16x16x32_bf16(wa, pf1, c2[tt], 0, 0, 0);
        }

        bf16x8 qf0, qf1;
        #pragma unroll
        for (int q = 0; q < 4; ++q) {
            qf0[q]     = f2bf(fast_tanh(c2[0][q]));
            qf0[4 + q] = f2bf(fast_tanh(c2[1][q]));
            qf1[q]     = f2bf(fast_tanh(c2[2][q]));
            qf1[4 + q] = f2bf(fast_tanh(c2[3][q]));
        }

        // ---- layer 3: w3f loaded fresh ----
        const bf16x8 w30 = *reinterpret_cast<const bf16x8*>(Af3);
        const bf16x8 w31 = *reinterpret_cast<const bf16x8*>(Af3 + 512);
        f32x4 c3 = {0.0f, 0.0f, 0.0f, 0.0f};
        c3 = __builtin_amdgcn_mfma_f32_16x16x32_bf16(w30, qf0, c3, 0, 0, 0);
        c3 = __builtin_amdgcn_mfma_f32_16x16x32_bf16(w31, qf1, c3, 0, 0, 0);

        if (g == 0) {
            const int row = rowW + 16 * grp;
            const float mu = c3[0] + b30;
            const float al = c3[1] + b31;
            const float xn = x[(size_t)row * 64 + l + 1];   // f32 input
            const float zv = (xn - mu) * fast_exp(-al);
            zT[(62 - l) * BATCHN + row] = zv;
            aT[l * BATCHN + row] = al;
        }
    }
}

// 256 blocks x 64 rows: log_det + z col 0 + LDS transpose -> coalesced z_out.
__global__ __launch_bounds__(256) void maf_finish_kernel(
    const float* __restrict__ x,
    const float* __restrict__ ip,
    const float* __restrict__ zT,
    const float* __restrict__ aT,
    float* __restrict__ z_out,
    float* __restrict__ ld_out)
{
    __shared__ float tile[64][65];

    const int t = threadIdx.x;
    const int rb = blockIdx.x * 64;
    const float mu0 = ip[0];
    const float a0  = ip[1];
    const float e0  = fast_exp(-a0);

    // log_det: 4 lanes per row, shfl reduce
    {
        const int r = t >> 2, c = t & 3;
        const int row = rb + r;
        float s = 0.0f;
        for (int i = c; i < LN; i += 4) s += aT[(size_t)i * BATCHN + row];
        s += __shfl_xor(s, 1, 64);
        s += __shfl_xor(s, 2, 64);
        if (c == 0) ld_out[row] = -(s + a0);
    }

    // transpose 64 rows x 64 cols
    const int r = t & 63, cq = t >> 6;
    #pragma unroll
    for (int k = 0; k < 16; ++k) {
        const int c = cq * 16 + k;
        float v;
        if (c < 63) v = zT[(size_t)c * BATCHN + rb + r];
        else        v = (x[(size_t)(rb + r) * 64] - mu0) * e0;  // z col 0 -> cr 63
        tile[c][r] = v;
    }
    __syncthreads();
    #pragma unroll
    for (int i = 0; i < 16; ++i) {
        const int rr = cq * 16 + i;
        z_out[(size_t)(rb + rr) * 64 + r] = tile[r][rr];
    }
}

extern "C" void kernel_launch(void* const* d_in, const int* in_sizes, int n_in,
                              void* d_out, int out_size, void* d_ws, size_t ws_size,
                              hipStream_t stream) {
    const float* x  = (const float*)d_in[0];
    const float* ip = (const float*)d_in[1];
    const float* W1 = (const float*)d_in[2];
    const float* b1 = (const float*)d_in[3];
    const float* W2 = (const float*)d_in[4];
    const float* b2 = (const float*)d_in[5];
    const float* W3 = (const float*)d_in[6];
    const float* b3 = (const float*)d_in[7];

    float* z_out  = (float*)d_out;                     // [16384][64] (reversed cols)
    float* ld_out = z_out + (size_t)BATCHN * 64;       // [16384]

    // ws layout: Afrag [63*9216 u16 = 1.16MB] | zT 4.13MB | aT 4.13MB | xbf 2MB
    unsigned short* Afrag = (unsigned short*)d_ws;
    float* zT = (float*)((char*)d_ws + (size_t)LN * 9216 * 2);
    float* aT = zT + (size_t)LN * BATCHN;
    unsigned short* xbf = (unsigned short*)(aT + (size_t)LN * BATCHN);

    prep_kernel<<<dim3(LN + BATCHN * 64 / 1024), dim3(256), 0, stream>>>(
        x, W1, b1, W2, W3, Afrag, xbf);
    maf_main_kernel<<<dim3(LN * 256), dim3(64), 0, stream>>>(
        x, xbf, Afrag, b2, b3, zT, aT);
    maf_finish_kernel<<<dim3(BATCHN / 64), dim3(256), 0, stream>>>(
        x, ip, zT, aT, z_out, ld_out);
}

// Round 19
// 67.502 us; speedup vs baseline: 1.0513x; 1.0137x over previous
//
#include <hip/hip_runtime.h>

#define LN 63
#define BATCHN 16384

typedef __attribute__((ext_vector_type(8))) short bf16x8;   // 8 bf16 in 4 VGPRs
typedef __attribute__((ext_vector_type(4))) float f32x4;

#define TBL_N     4096
#define TBL_SCALE 431.157894f          // entries per unit: 4096 / 9.5
#define TBL_BIAS  2048.5f              // +0.5: cvt_u32 truncation = round

__device__ __forceinline__ float fast_exp(float v) {
    return __builtin_amdgcn_exp2f(v * 1.4426950408889634f);
}
__device__ __forceinline__ float fast_tanh(float v) {
    float e = __builtin_amdgcn_exp2f(v * 2.8853900817779268f); // e^{2v}
    return 1.0f - 2.0f * __builtin_amdgcn_rcpf(e + 1.0f);
}
__device__ __forceinline__ short f2bf(float f) {
    __bf16 h = (__bf16)f;
    return __builtin_bit_cast(short, h);
}
__device__ __forceinline__ unsigned int pk2(float a, float b) {
    return (unsigned int)(unsigned short)f2bf(a) |
           ((unsigned int)(unsigned short)f2bf(b) << 16);
}

// kappa j-index for W2/W3 fragment element e (derived from R6's verified LDS
// reads): e<4 -> 32s+4g+e ; e>=4 -> 32s+16+4g+(e-4).
__device__ __forceinline__ int kappa_j(int s, int g, int e) {
    return (e < 4) ? (32 * s + 4 * g + e) : (32 * s + 16 + 4 * g + e - 4);
}

// Combined prep: blocks 0..62 write per-lane fragment-ordered bf16 weights
// into Afrag[l] (18432 B per l); blocks 63.. convert x -> xbf.  (R9-verified)
__global__ __launch_bounds__(256) void prep_kernel(
    const float* __restrict__ x,
    const float* __restrict__ W1, const float* __restrict__ b1,
    const float* __restrict__ W2, const float* __restrict__ W3,
    unsigned short* __restrict__ Afrag,
    unsigned short* __restrict__ xbf)
{
    const int t = threadIdx.x;
    const int b = blockIdx.x;
    if (b >= LN) {
        const int i = ((b - LN) * 256 + t) * 4;
        const float4 v = *reinterpret_cast<const float4*>(x + i);
        ushort4 o;
        o.x = (unsigned short)f2bf(v.x);
        o.y = (unsigned short)f2bf(v.y);
        o.z = (unsigned short)f2bf(v.z);
        o.w = (unsigned short)f2bf(v.w);
        *reinterpret_cast<ushort4*>(xbf + i) = o;
        return;
    }
    const int l = b;
    unsigned short* Af = Afrag + (size_t)l * 9216;

    // A1: 512 items (s,tt,lane), 2 per thread
    #pragma unroll
    for (int it = 0; it < 2; ++it) {
        const int item = t + it * 256;
        const int s = item >> 8, tt = (item >> 6) & 3, lane = item & 63;
        const int g = lane >> 4, mcol = lane & 15, h = 16 * tt + mcol;
        unsigned pk[4];
        #pragma unroll
        for (int ep = 0; ep < 4; ++ep) {
            float v[2];
            #pragma unroll
            for (int k = 0; k < 2; ++k) {
                const int e = 2 * ep + k;
                const int j = 32 * s + 8 * g + e;
                float val;
                if (j == 63)      val = b1[l * 64 + h];
                else if (j <= l)  val = W1[(l * LN + j) * 64 + h];
                else              val = 0.0f;
                v[k] = val;
            }
            pk[ep] = pk2(v[0], v[1]);
        }
        *reinterpret_cast<uint4*>(Af + ((size_t)item) * 8) =
            uint4{pk[0], pk[1], pk[2], pk[3]};
    }
    // A2: 512 items
    #pragma unroll
    for (int it = 0; it < 2; ++it) {
        const int item = t + it * 256;
        const int s = item >> 8, tt = (item >> 6) & 3, lane = item & 63;
        const int g = lane >> 4, mcol = lane & 15, h = 16 * tt + mcol;
        unsigned pk[4];
        #pragma unroll
        for (int ep = 0; ep < 4; ++ep) {
            float v[2];
            #pragma unroll
            for (int k = 0; k < 2; ++k) {
                const int e = 2 * ep + k;
                v[k] = W2[(l * 64 + kappa_j(s, g, e)) * 64 + h];
            }
            pk[ep] = pk2(v[0], v[1]);
        }
        *reinterpret_cast<uint4*>(Af + 4096 + ((size_t)item) * 8) =
            uint4{pk[0], pk[1], pk[2], pk[3]};
    }
    // A3: 128 items (s,lane)
    if (t < 128) {
        const int s = t >> 6, lane = t & 63;
        const int g = lane >> 4, mcol = lane & 15;
        unsigned pk[4] = {0u, 0u, 0u, 0u};
        if (mcol < 2) {
            #pragma unroll
            for (int ep = 0; ep < 4; ++ep) {
                float v[2];
                #pragma unroll
                for (int k = 0; k < 2; ++k) {
                    const int e = 2 * ep + k;
                    v[k] = W3[(l * 64 + kappa_j(s, g, e)) * 2 + mcol];
                }
                pk[ep] = pk2(v[0], v[1]);
            }
        }
        *reinterpret_cast<uint4*>(Af + 8192 + ((size_t)t) * 8) =
            uint4{pk[0], pk[1], pk[2], pk[3]};
    }
}

// Block = one l (0..62) x 1024 batch rows. Grid 63*16 = 1008.
// R18: TANH VIA LDS LOOKUP TABLE. R9-R17 showed the kernel issue-bound on the
// VALU/trans port (~980 cyc/grp demand, trans-dominated: 64 quarter-rate
// exp/rcp = 512 cyc) with the DS pipe COMPLETELY IDLE. The 4096-entry bf16
// tanh table (8KB LDS, [-4.75,4.75], filled once per block) converts each
// tanh+f2bf (~24 cyc VALU/trans) into 4 VALU (8 cyc) + 1 ds_read_u16 on the
// parallel DS pipe. Weights remain staging-free via Afrag (R15-verified).
__global__ __launch_bounds__(256) void maf_main_kernel(
    const float* __restrict__ x,
    const unsigned short* __restrict__ xbf,
    const unsigned short* __restrict__ Afrag,
    const float* __restrict__ b2,
    const float* __restrict__ b3,
    float* __restrict__ zT,   // ws: [63][BATCH] row cr=62-l (z col l+1 reversed)
    float* __restrict__ aT)   // ws: [63][BATCH] alpha col l+1
{
    __shared__ unsigned short tanh_tbl[TBL_N];

    const int t = threadIdx.x;
    const int bid = blockIdx.x;
    const int l = bid % LN;                 // block-uniform
    const int rowBase = (bid / LN) * 1024;

    // ---- fill tanh table: 16 entries/thread, amortized over 16 grps ----
    #pragma unroll
    for (int i = 0; i < 16; ++i) {
        const int idx = t + i * 256;
        const float v = ((float)idx - 2048.0f) * (1.0f / TBL_SCALE);
        tanh_tbl[idx] = (unsigned short)f2bf(fast_tanh(v));
    }
    __syncthreads();

    const int lane = t & 63;
    const int w = t >> 6;
    const int g = lane >> 4;
    const int mcol = lane & 15;

    const unsigned short* Af = Afrag + (size_t)l * 9216;
    const unsigned short* Af1 = Af + lane * 8;           // w1f base (per-lane)
    const unsigned short* Af2 = Af + 4096 + lane * 8;    // w2f base
    const unsigned short* Af3 = Af + 8192 + lane * 8;    // w3f base

    // tanh lookup: fma + med3-clamp + cvt + (lshl folded in ds addressing)
    auto lut = [&](float v) -> short {
        float bf = fmaf(v, TBL_SCALE, TBL_BIAS);
        bf = __builtin_amdgcn_fmed3f(bf, 0.0f, 4095.0f);   // clamp [0,4095]
        return (short)tanh_tbl[(unsigned)bf];
    };

    f32x4 bias2[4];
    #pragma unroll
    for (int tt = 0; tt < 4; ++tt) {
        const float4 v2 = *reinterpret_cast<const float4*>(&b2[l * 64 + 16 * tt + 4 * g]);
        bias2[tt] = f32x4{v2.x, v2.y, v2.z, v2.w};
    }
    const float b30 = b3[l * 2 + 0];
    const float b31 = b3[l * 2 + 1];
    const short one_bf = (short)0x3F80;   // bf16(1.0)

    const int rowW = rowBase + w * 256 + mcol;
    const unsigned short* xrow = xbf + (size_t)rowW * 64 + 8 * g;

    // ---------------- 16 groups of 16 rows per wave ----------------
    #pragma unroll 1
    for (int grp = 0; grp < 16; ++grp) {
        const unsigned short* xp = xrow + (size_t)(16 * grp) * 64;

        bf16x8 xf0 = *reinterpret_cast<const bf16x8*>(xp);
        bf16x8 xf1 = *reinterpret_cast<const bf16x8*>(xp + 32);
        if (g == 3) xf1[7] = one_bf;   // b1 k-slot 63 pairs with 1.0

        // ---- layer 1: w1f loaded fresh (L1-hot) ----
        f32x4 c1[4];
        #pragma unroll
        for (int tt = 0; tt < 4; ++tt) {
            const bf16x8 wa = *reinterpret_cast<const bf16x8*>(Af1 + (0 * 4 + tt) * 512);
            c1[tt] = __builtin_amdgcn_mfma_f32_16x16x32_bf16(
                wa, xf0, f32x4{0.0f, 0.0f, 0.0f, 0.0f}, 0, 0, 0);
        }
        #pragma unroll
        for (int tt = 0; tt < 4; ++tt) {
            const bf16x8 wa = *reinterpret_cast<const bf16x8*>(Af1 + (1 * 4 + tt) * 512);
            c1[tt] = __builtin_amdgcn_mfma_f32_16x16x32_bf16(wa, xf1, c1[tt], 0, 0, 0);
        }

        // ---- tanh via LDS table (DS pipe) + pack ----
        bf16x8 pf0, pf1;
        #pragma unroll
        for (int q = 0; q < 4; ++q) {
            pf0[q]     = lut(c1[0][q]);
            pf0[4 + q] = lut(c1[1][q]);
            pf1[q]     = lut(c1[2][q]);
            pf1[4 + q] = lut(c1[3][q]);
        }

        // ---- layer 2: w2f loaded fresh ----
        f32x4 c2[4];
        #pragma unroll
        for (int tt = 0; tt < 4; ++tt) {
            const bf16x8 wa = *reinterpret_cast<const bf16x8*>(Af2 + (0 * 4 + tt) * 512);
            c2[tt] = __builtin_amdgcn_mfma_f32_16x16x32_bf16(wa, pf0, bias2[tt], 0, 0, 0);
        }
        #pragma unroll
        for (int tt = 0; tt < 4; ++tt) {
            const bf16x8 wa = *reinterpret_cast<const bf16x8*>(Af2 + (1 * 4 + tt) * 512);
            c2[tt] = __builtin_amdgcn_mfma_f32_16x16x32_bf16(wa, pf1, c2[tt], 0, 0, 0);
        }

        bf16x8 qf0, qf1;
        #pragma unroll
        for (int q = 0; q < 4; ++q) {
            qf0[q]     = lut(c2[0][q]);
            qf0[4 + q] = lut(c2[1][q]);
            qf1[q]     = lut(c2[2][q]);
            qf1[4 + q] = lut(c2[3][q]);
        }

        // ---- layer 3: w3f loaded fresh ----
        const bf16x8 w30 = *reinterpret_cast<const bf16x8*>(Af3);
        const bf16x8 w31 = *reinterpret_cast<const bf16x8*>(Af3 + 512);
        f32x4 c3 = {0.0f, 0.0f, 0.0f, 0.0f};
        c3 = __builtin_amdgcn_mfma_f32_16x16x32_bf16(w30, qf0, c3, 0, 0, 0);
        c3 = __builtin_amdgcn_mfma_f32_16x16x32_bf16(w31, qf1, c3, 0, 0, 0);

        if (g == 0) {
            const int row = rowW + 16 * grp;
            const float mu = c3[0] + b30;
            const float al = c3[1] + b31;
            const float xn = x[(size_t)row * 64 + l + 1];   // f32 input
            const float zv = (xn - mu) * fast_exp(-al);
            zT[(62 - l) * BATCHN + row] = zv;
            aT[l * BATCHN + row] = al;
        }
    }
}

// 256 blocks x 64 rows: log_det + z col 0 + LDS transpose -> coalesced z_out.
__global__ __launch_bounds__(256) void maf_finish_kernel(
    const float* __restrict__ x,
    const float* __restrict__ ip,
    const float* __restrict__ zT,
    const float* __restrict__ aT,
    float* __restrict__ z_out,
    float* __restrict__ ld_out)
{
    __shared__ float tile[64][65];

    const int t = threadIdx.x;
    const int rb = blockIdx.x * 64;
    const float mu0 = ip[0];
    const float a0  = ip[1];
    const float e0  = fast_exp(-a0);

    // log_det: 4 lanes per row, shfl reduce
    {
        const int r = t >> 2, c = t & 3;
        const int row = rb + r;
        float s = 0.0f;
        for (int i = c; i < LN; i += 4) s += aT[(size_t)i * BATCHN + row];
        s += __shfl_xor(s, 1, 64);
        s += __shfl_xor(s, 2, 64);
        if (c == 0) ld_out[row] = -(s + a0);
    }

    // transpose 64 rows x 64 cols
    const int r = t & 63, cq = t >> 6;
    #pragma unroll
    for (int k = 0; k < 16; ++k) {
        const int c = cq * 16 + k;
        float v;
        if (c < 63) v = zT[(size_t)c * BATCHN + rb + r];
        else        v = (x[(size_t)(rb + r) * 64] - mu0) * e0;  // z col 0 -> cr 63
        tile[c][r] = v;
    }
    __syncthreads();
    #pragma unroll
    for (int i = 0; i < 16; ++i) {
        const int rr = cq * 16 + i;
        z_out[(size_t)(rb + rr) * 64 + r] = tile[r][rr];
    }
}

extern "C" void kernel_launch(void* const* d_in, const int* in_sizes, int n_in,
                              void* d_out, int out_size, void* d_ws, size_t ws_size,
                              hipStream_t stream) {
    const float* x  = (const float*)d_in[0];
    const float* ip = (const float*)d_in[1];
    const float* W1 = (const float*)d_in[2];
    const float* b1 = (const float*)d_in[3];
    const float* W2 = (const float*)d_in[4];
    const float* b2 = (const float*)d_in[5];
    const float* W3 = (const float*)d_in[6];
    const float* b3 = (const float*)d_in[7];

    float* z_out  = (float*)d_out;                     // [16384][64] (reversed cols)
    float* ld_out = z_out + (size_t)BATCHN * 64;       // [16384]

    // ws layout: Afrag [63*9216 u16 = 1.16MB] | zT 4.13MB | aT 4.13MB | xbf 2MB
    unsigned short* Afrag = (unsigned short*)d_ws;
    float* zT = (float*)((char*)d_ws + (size_t)LN * 9216 * 2);
    float* aT = zT + (size_t)LN * BATCHN;
    unsigned short* xbf = (unsigned short*)(aT + (size_t)LN * BATCHN);

    prep_kernel<<<dim3(LN + BATCHN * 64 / 1024), dim3(256), 0, stream>>>(
        x, W1, b1, W2, W3, Afrag, xbf);
    maf_main_kernel<<<dim3(LN * 16), dim3(256), 0, stream>>>(
        x, xbf, Afrag, b2, b3, zT, aT);
    maf_finish_kernel<<<dim3(BATCHN / 64), dim3(256), 0, stream>>>(
        x, ip, zT, aT, z_out, ld_out);
}